// Round 6
// baseline (9045.213 us; speedup 1.0000x reference)
//
#include <hip/hip_runtime.h>

// 6 chained LSTM passes (0-4 share W1/U1/b1, 5 uses W2/U2/b2). B=128,T=256,H=512.
// v7: robustness-first rebuild. 128 wgs (verified-residency scale) x 512 thr
// (8 waves) = 8 rowgroups(16 rows) x 16 wgs(32 units = 128 z-cols).
// ONLY v1-harness-verified memory primitives (__hip_atomic_* AGENT scope =
// sc0 sc1, LLC-coherent); no cache-policy inline asm; no cooperative launch;
// plain <<<128,512>>>.
// Improvements over v1 kept:
//  * register-resident weights: each lane pre-stages its 32 16B B-fragments
//    into breg[32] (128 VGPR, all indices compile-time). No weight LDS, no
//    weight ds_reads, staging is wave-private (no barriers).
//  * LDS-staged A-slices: each wg stages the 16KB h-slice (and x-slice for
//    layers 1+) ONCE (512 thr x 32B, XOR-swizzle byte^=(row&7)<<4), all 8
//    waves read via conflict-free ds_read_b128 -> 4x less LLC slice traffic
//    than v1 (4MB/step vs 16MB/step).
//  * per-wave flag bytes: wave w stores byte w of its wg's flag dword after a
//    wave-level s_waitcnt vmcnt(0) (h-stores acked first). Consumers ballot
//    32 dwords == 0x01010101. No producer-side __syncthreads before publish.
//  * x-slice prefetch: next step's x loads issue AFTER the flag store, so the
//    publish drain never waits on them; they complete during the next step's
//    stage/poll (compiler-inserted waitcnt), off the inter-wg critical chain.
// Two barriers/step (B1 Abx, B2 Abh) cover all LDS WAR hazards (uniform
// branches -> consistent barrier pairing). c-state in registers all 6 layers.
// CAP=260 ring: oldest live read (x-prefetch) is slice s-255, retired 5 steps
// before slot reuse; flag poll transitively orders all reuse. Flags cleared
// per launch by hipMemsetAsync -> graph-replay safe (H never read stale).

#define TSEQ  256
#define HID   512
#define CAP   260
#define WPR   32
#define NSTEP 1536
#define NWG   128
#define NTHR  512

typedef _Float16 v8h __attribute__((ext_vector_type(8)));
typedef float    v4f __attribute__((ext_vector_type(4)));

__device__ __forceinline__ float sigm(float x)  { return 1.0f / (1.0f + __expf(-x)); }
__device__ __forceinline__ float tanhf_(float x){ return 1.0f - 2.0f / (__expf(2.0f * x) + 1.0f); }

// AGENT scope = sc0 sc1 (L1+L2 bypass, LLC coherence point). v1-verified.
__device__ __forceinline__ unsigned long long ld8(const unsigned long long* p) {
    return __hip_atomic_load(p, __ATOMIC_RELAXED, __HIP_MEMORY_SCOPE_AGENT);
}
__device__ __forceinline__ unsigned ld4(const unsigned* p) {
    return __hip_atomic_load(p, __ATOMIC_RELAXED, __HIP_MEMORY_SCOPE_AGENT);
}
__device__ __forceinline__ void st4(unsigned* p, unsigned v) {
    __hip_atomic_store(p, v, __ATOMIC_RELAXED, __HIP_MEMORY_SCOPE_AGENT);
}
__device__ __forceinline__ void stb(unsigned char* p, unsigned char v) {
    __hip_atomic_store(p, v, __ATOMIC_RELAXED, __HIP_MEMORY_SCOPE_AGENT);
}

// A-fragment (ds_read_b128) from swizzled 16KB slice [16 rows][1024B]
#define AF(Ab, kc) (*(const v8h*)((const char*)(Ab) + arow + ((aoff + ((kc) << 6)) ^ aswz)))

__global__ __launch_bounds__(NTHR, 2)
void lstm_persist(const float* __restrict__ x,
                  const float* __restrict__ W1, const float* __restrict__ U1,
                  const float* __restrict__ b1,
                  const float* __restrict__ W2, const float* __restrict__ U2,
                  const float* __restrict__ b2,
                  float* __restrict__ out,
                  _Float16* __restrict__ H,     // [8][CAP][16][512] f16
                  unsigned* __restrict__ FL) {  // [8][NSTEP][32] dwords (4 wave-bytes each)
    const int wg  = blockIdx.x;
    const int tid = threadIdx.x;
    const int r   = wg & 7;              // rowgroup: rows [r*16, r*16+16)
    const int wc  = wg >> 3;             // 0..15: units [wc*32, wc*32+32)

    __shared__ __attribute__((aligned(16))) char SM[32768];
    char* const Abx = SM;                // [0,16K): x-slice A-buffer
    char* const Abh = SM + 16384;        // [16K,32K): h-slice A-buffer

    const int lane = tid & 63;
    const int w    = tid >> 6;           // wave 0..7 -> col tile
    const int q    = lane >> 4;
    const int j4   = lane & 3;
    const int a4   = (lane & 15) >> 2;
    const int rl   = lane & 15;          // A row (local, 0..15)

    _Float16* const Hr  = H  + (size_t)r * CAP * 16 * HID;
    unsigned* const FLr = FL + (size_t)r * NSTEP * WPR;

    const int grow   = (r << 4) + rl;                      // A row (global batch)
    const int c0     = (w << 4) + rl;                      // local z-col 0..127
    const int gz0    = ((c0 & 3) << 9) + (wc << 5) + (c0 >> 2);  // global z-col
    const int erow_l = (q << 2) + j4;                      // epilogue row (local)
    const int grow_e = (r << 4) + erow_l;                  // epilogue row (global)
    const int Ut     = (wc << 5) + (w << 2) + a4;          // epilogue unit

    const int arow = rl << 10;                             // A-read row byte base
    const int aoff = q << 4;                               // A-read col byte base
    const int aswz = (rl & 7) << 4;                        // A-read swizzle

    // staging map: thread owns 8B at linear byte j*4096 + tid*8 (j=0..3)
    int soff[4];
    #pragma unroll
    for (int j = 0; j < 4; ++j) {
        const int L   = (j << 12) + (tid << 3);
        const int row = L >> 10;
        soff[j] = L ^ ((row & 7) << 4);
    }

    v8h breg[32];                        // 128 VGPR: all B-fragments this lane uses
    unsigned long long xx[4] = {0, 0, 0, 0};
    float cs = 0.0f;
    float bI = 0.f, bF = 0.f, bG = 0.f, bO = 0.f;

    for (int s = 0; s < NSTEP; ++s) {
        const int m = s >> 8;
        const int t = s & 255;

        // ---- weight staging into registers (layer 0 / layer 5 start).
        //      breg[kc]: k-elems (kc&15)*32 + q*8 .. +8 of col gz0;
        //      kc<16 -> W (x-part), kc>=16 -> U (h-part). Wave-private.
        if (s == 0 || s == 1280) {
            const float* Wg = s ? W2 : W1;
            const float* Ug = s ? U2 : U1;
            const float* bg = s ? b2 : b1;
            #pragma unroll
            for (int kc = 0; kc < 32; ++kc) {
                const float* src = (kc < 16)
                    ? (Wg + (size_t)((kc << 5) + (q << 3)) * 2048 + gz0)
                    : (Ug + (size_t)(((kc - 16) << 5) + (q << 3)) * 2048 + gz0);
                v8h v;
                #pragma unroll
                for (int j = 0; j < 8; ++j) v[j] = (_Float16)src[(size_t)j * 2048];
                breg[kc] = v;
            }
            bI = bg[Ut]; bF = bg[512 + Ut]; bG = bg[1024 + Ut]; bO = bg[1536 + Ut];
        }

        v4f acc[4];
        #pragma unroll
        for (int i = 0; i < 4; ++i) acc[i] = v4f{0.f, 0.f, 0.f, 0.f};

        // ---- x phase (k 0..511): entirely before the poll ----
        if (m == 0) {
            // layer 0: direct from x (f32 -> f16 cvt), L1/L2-cached plain loads
            const float* xp = x + ((size_t)grow * TSEQ + t) * HID + (q << 3);
            #pragma unroll
            for (int kc = 0; kc < 16; ++kc) {
                const float4 f0 = *(const float4*)(xp + (kc << 5));
                const float4 f1 = *(const float4*)(xp + (kc << 5) + 4);
                v8h a;
                a[0] = (_Float16)f0.x; a[1] = (_Float16)f0.y;
                a[2] = (_Float16)f0.z; a[3] = (_Float16)f0.w;
                a[4] = (_Float16)f1.x; a[5] = (_Float16)f1.y;
                a[6] = (_Float16)f1.z; a[7] = (_Float16)f1.w;
                acc[kc & 3] = __builtin_amdgcn_mfma_f32_16x16x32_f16(a, breg[kc], acc[kc & 3], 0, 0, 0);
            }
        } else {
            // layers 1+: xx prefetched at tail of step s-1 (compiler inserts
            // the vmcnt wait here); stage swizzled, then MFMA from LDS.
            #pragma unroll
            for (int j = 0; j < 4; ++j)
                *(unsigned long long*)(Abx + soff[j]) = xx[j];
            __syncthreads();                               // B1: Abx visible
            #pragma unroll
            for (int kc = 0; kc < 16; ++kc)
                acc[kc & 3] = __builtin_amdgcn_mfma_f32_16x16x32_f16(AF(Abx, kc), breg[kc], acc[kc & 3], 0, 0, 0);
        }

        // ---- wait for all 8 waves of all 16 wgs of this rowgroup @ step s-1 ----
        if (s > 0) {
            const unsigned* fp = FLr + (size_t)(s - 1) * WPR + (lane & 31);
            while (true) {
                const unsigned v = ld4(fp);
                if (__ballot(v == 0x01010101u) == ~0ull) break;
                __builtin_amdgcn_s_sleep(1);
            }
            asm volatile("" ::: "memory");

            // ---- h phase (k 512..1023): pull slice s-1, stage, MFMA ----
            const unsigned long long* hq =
                (const unsigned long long*)(Hr + (size_t)((s - 1) % CAP) * 16 * HID);
            unsigned long long hx[4];
            #pragma unroll
            for (int j = 0; j < 4; ++j) hx[j] = ld8(hq + (j << 9) + tid);
            #pragma unroll
            for (int j = 0; j < 4; ++j)
                *(unsigned long long*)(Abh + soff[j]) = hx[j];
            __syncthreads();                               // B2: Abh visible
            #pragma unroll
            for (int kc = 0; kc < 16; ++kc)
                acc[kc & 3] = __builtin_amdgcn_mfma_f32_16x16x32_f16(AF(Abh, kc), breg[16 + kc], acc[kc & 3], 0, 0, 0);
        }

        const v4f tt = (acc[0] + acc[1]) + (acc[2] + acc[3]);

        // ---- 4x4 quad transpose (within 16-lane groups) ----
        float A0 = tt[0], A1 = tt[1], A2 = tt[2], A3 = tt[3];
        {
            float t0 = __shfl_xor(A1, 1, 64), t1 = __shfl_xor(A0, 1, 64);
            float t2 = __shfl_xor(A3, 1, 64), t3 = __shfl_xor(A2, 1, 64);
            if (j4 & 1) { A0 = t0; A2 = t2; }
            else        { A1 = t1; A3 = t3; }
        }
        {
            float t0 = __shfl_xor(A2, 2, 64), t1 = __shfl_xor(A3, 2, 64);
            float t2 = __shfl_xor(A0, 2, 64), t3 = __shfl_xor(A1, 2, 64);
            if (j4 & 2) { A0 = t0; A1 = t1; }
            else        { A2 = t2; A3 = t3; }
        }
        // lane now holds gates [i,f,g,o] for (grow_e, Ut) in A0..A3

        const float ig = sigm(A0 + bI), fg = sigm(A1 + bF);
        const float gg = tanhf_(A2 + bG), og = sigm(A3 + bO);
        cs = fg * cs + ig * gg;
        const float hv = og * tanhf_(cs);

        if (s < NSTEP - 1) {
            // pack adjacent units (a4, a4^1) into a dword via shfl, store
            const int sw = s % CAP;
            unsigned* const hwp = (unsigned*)(Hr + ((size_t)sw * 16 + erow_l) * HID);
            const unsigned hb = (unsigned)__builtin_bit_cast(unsigned short, (_Float16)hv);
            const unsigned ob = (unsigned)__shfl_xor((int)hb, 4, 64);
            if ((a4 & 1) == 0) st4(hwp + (Ut >> 1), hb | (ob << 16));
            // per-wave publish: wave-level vmcnt(0) drains this wave's h-stores
            // to the coherence point, then lane 0 sets flag byte w.
            asm volatile("s_waitcnt vmcnt(0)" ::: "memory");
            if (lane == 0)
                stb((unsigned char*)(FLr + (size_t)s * WPR + ((wc << 1) | (w >> 2))) + (w & 3), 1);
        } else {
            out[(size_t)grow_e * HID + Ut] = hv;
        }

        // ---- prefetch next step's x-slice (layer m>=1 input = slice s-255).
        //      Issued AFTER the flag store: never delays the publish; completes
        //      during next step's stage (compiler waitcnt) / producers' work.
        if (s >= 255 && s < NSTEP - 1) {
            const unsigned long long* xq =
                (const unsigned long long*)(Hr + (size_t)((s - 255) % CAP) * 16 * HID);
            #pragma unroll
            for (int j = 0; j < 4; ++j) xx[j] = ld8(xq + (j << 9) + tid);
        }
    }
}

extern "C" void kernel_launch(void* const* d_in, const int* in_sizes, int n_in,
                              void* d_out, int out_size, void* d_ws, size_t ws_size,
                              hipStream_t stream) {
    (void)in_sizes; (void)n_in; (void)out_size;
    const size_t SZ_H  = (size_t)8 * CAP * 16 * HID * sizeof(_Float16); // 34,078,720
    const size_t SZ_FL = (size_t)8 * NSTEP * WPR * sizeof(unsigned);   //  1,572,864
    const size_t NEED  = SZ_H + SZ_FL;
    if (ws_size < NEED) return;

    char* ws = (char*)d_ws;
    hipMemsetAsync(ws + SZ_H, 0, SZ_FL, stream);   // clear flags (graph-replay safe)

    lstm_persist<<<NWG, NTHR, 0, stream>>>(
        (const float*)d_in[0],
        (const float*)d_in[1], (const float*)d_in[2], (const float*)d_in[3],
        (const float*)d_in[4], (const float*)d_in[5], (const float*)d_in[6],
        (float*)d_out,
        (_Float16*)ws,
        (unsigned*)(ws + SZ_H));
}